// Round 6
// baseline (145.994 us; speedup 1.0000x reference)
//
#include <hip/hip_runtime.h>
#include <math.h>

// Problem constants
#define NVOX  32768     // 32^3 up-res voxels
#define CIN   64
#define COUT  32
#define KT    27
#define CIT   1728      // CIN*KT
#define PSP   5832      // 18^3 padded half-res spatial

// Workspace layout (float offsets)
#define WS_XT   0                 // fp16[5832][64] channel-last padded x
#define WS_WA   186624            // fp16[216][32][8] deform-W A-frags (K tap-major)
#define WS_W2   214272            // fp16[8][64][96][8] parity-collapsed offset-W frags
#define WS_STAT 410880            // [32] sum, [32] sumsq
#define WS_P    410944            // fp16[81][32768] offsets (m-major), 5.31 MB

typedef __attribute__((ext_vector_type(8))) _Float16 half8;
typedef __attribute__((ext_vector_type(2))) _Float16 half2v;
typedef __attribute__((ext_vector_type(4))) float floatx4;
typedef __attribute__((ext_vector_type(4))) int i4;

static __device__ __forceinline__ unsigned dup16(float w) {
    unsigned short b = __builtin_bit_cast(unsigned short, (_Float16)w);
    return (unsigned)b * 0x10001u;
}
static __device__ __forceinline__ half2v u2h2(unsigned u) {
    return __builtin_bit_cast(half2v, u);
}
static __device__ __forceinline__ half8 pk8(half2v a, half2v b, half2v c, half2v d) {
    union { half8 v; half2v p[4]; } u;
    u.p[0] = a; u.p[1] = b; u.p[2] = c; u.p[3] = d;
    return u.v;
}

// ---------------------------------------------------------------------------
// Merged prep (UNCHANGED from round 5 — verified).
// ---------------------------------------------------------------------------
__global__ __launch_bounds__(256) void prep_all_kernel(
        const float* __restrict__ x, const float* __restrict__ w_off,
        const float* __restrict__ wmat, float* __restrict__ ws) {
    int b = blockIdx.x, t = threadIdx.x;
    if (b < 92) {
        __shared__ _Float16 tile[64][65];
        _Float16* xth = (_Float16*)(ws + WS_XT);
        int tq = t >> 6, lane = t & 63;
        int base = b * 64;
        int cell = base + lane;
        int qw = cell % 18, qh = (cell / 18) % 18, qd = cell / 324;
        bool interior = (cell < PSP) && qd >= 1 && qd <= 16 && qh >= 1 && qh <= 16
                        && qw >= 1 && qw <= 16;
        int xbase = interior ? (((qd - 1) * 16 + (qh - 1)) * 16 + (qw - 1)) : 0;
#pragma unroll
        for (int i = 0; i < 16; i++) {
            int c = tq * 16 + i;
            float v = interior ? x[c * 4096 + xbase] : 0.f;
            tile[lane][c] = (_Float16)v;
        }
        __syncthreads();
#pragma unroll
        for (int i = 0; i < 16; i++) {
            int s = tq * 16 + i;
            int cell2 = base + s;
            if (cell2 < PSP) xth[cell2 * 64 + lane] = tile[s][lane];
        }
    } else if (b < 119) {
        _Float16* wa = (_Float16*)(ws + WS_WA);
        int idx = (b - 92) * 256 + t;           // 0..6911  (kb, o)
        int kb = idx >> 5, o = idx & 31;
        half8 r;
#pragma unroll
        for (int j = 0; j < 8; j++) {
            int kk = kb * 8 + j;                // K index, tap-major
            int tap = kk >> 6, ci = kk & 63;
            r[j] = (_Float16)wmat[o * CIT + ci * 27 + tap];
        }
        *(half8*)(wa + idx * 8) = r;
    } else if (b < 311) {
        _Float16* w2 = (_Float16*)(ws + WS_W2);
        int idx = (b - 119) * 256 + t;          // 0..49151 = (pi*64 + kb)*96 + m
        int pi = idx / 6144;
        int rem = idx - pi * 6144;
        int kb = rem / 96, m = rem - (rem / 96) * 96;
        int pid = pi >> 2, pih = (pi >> 1) & 1, piw = pi & 1;
        half8 r;
#pragma unroll
        for (int j = 0; j < 8; j++) {
            int kk = kb * 8 + j;                // K in [0,512)
            int tap2 = kk >> 6, ci = kk & 63;
            int cd = tap2 >> 2, ch = (tap2 >> 1) & 1, cw = tap2 & 1;
            int bd = pid ? (cd ? 2 : 0) : cd;
            int nd = pid ? (cd ? 1 : 2) : (cd ? 2 : 1);
            int bh = pih ? (ch ? 2 : 0) : ch;
            int nh = pih ? (ch ? 1 : 2) : (ch ? 2 : 1);
            int bw = piw ? (cw ? 2 : 0) : cw;
            int nw = piw ? (cw ? 1 : 2) : (cw ? 2 : 1);
            float s = 0.f;
            if (m < 81) {
                const float* wp = w_off + (m * 64 + ci) * 27;
                for (int a = 0; a < nd; a++)
                    for (int bb = 0; bb < nh; bb++)
                        for (int c = 0; c < nw; c++)
                            s += wp[(bd + a) * 9 + (bh + bb) * 3 + (bw + c)];
            }
            r[j] = (_Float16)s;
        }
        *(half8*)(w2 + idx * 8) = r;
    } else {
        if (t < 64) ws[WS_STAT + t] = 0.f;
    }
}

// ---------------------------------------------------------------------------
// Kernel A: parity-collapsed offset GEMM (UNCHANGED from round 5 — verified).
// ---------------------------------------------------------------------------
__global__ __launch_bounds__(256, 4) void offset_kernel(
        const float* __restrict__ b_off, float* ws) {
    __shared__ __align__(16) _Float16 abuf[2 * 6144];   // 2 x 12288 B
    int tid = threadIdx.x, wave = tid >> 6, lane = tid & 63;
    int nsub = wave & 1, kh = wave >> 1;
    int col = lane & 15, quad = lane >> 4;
    int bid = blockIdx.x;
    int pi = bid >> 7, tile = bid & 127;
    int pid = pi >> 2, pih = (pi >> 1) & 1, piw = pi & 1;
    int qd = tile >> 3, qh = (tile & 7) * 2 + nsub;
    const char* xtb = (const char*)(ws + WS_XT);
    const int4* wsrc = (const int4*)(ws + WS_W2) + pi * 6144;
    _Float16* Pw = (_Float16*)(ws + WS_P);
    int4* ab4 = (int4*)abuf;

    int4 bx[8];
#pragma unroll
    for (int tap = 0; tap < 8; tap++) {
        int cd = tap >> 2, ch = (tap >> 1) & 1, cw = tap & 1;
        int cell = ((qd + cd + pid) * 18 + (qh + ch + pih)) * 18 + (col + cw + piw);
        bx[tap] = *(const int4*)(xtb + cell * 128 + kh * 64 + quad * 16);
    }

    int4 ra0 = wsrc[tid], ra1 = wsrc[256 + tid], ra2 = wsrc[512 + tid];
    ab4[tid] = ra0; ab4[256 + tid] = ra1; ab4[512 + tid] = ra2;
    ra0 = wsrc[768 + tid]; ra1 = wsrc[768 + 256 + tid]; ra2 = wsrc[768 + 512 + tid];
    __syncthreads();

    floatx4 acc[6];
#pragma unroll
    for (int mt = 0; mt < 6; mt++) acc[mt] = (floatx4){0.f, 0.f, 0.f, 0.f};

    int fb = (kh * 4 + quad) * 768 + col * 8;

#pragma unroll
    for (int tap = 0; tap < 8; tap++) {
        if (tap < 7) {
            int4* dst = ab4 + ((tap + 1) & 1) * 768;
            dst[tid] = ra0; dst[256 + tid] = ra1; dst[512 + tid] = ra2;
        }
        if (tap < 6) {
            const int4* s2 = wsrc + (tap + 2) * 768;
            ra0 = s2[tid]; ra1 = s2[256 + tid]; ra2 = s2[512 + tid];
        }
        half8 bfrag = __builtin_bit_cast(half8, bx[tap]);
        const _Float16* abh = abuf + (tap & 1) * 6144;
#pragma unroll
        for (int mt = 0; mt < 6; mt++) {
            half8 af = *(const half8*)(abh + fb + mt * 128);
            acc[mt] = __builtin_amdgcn_mfma_f32_16x16x32_f16(af, bfrag, acc[mt], 0, 0, 0);
        }
        __syncthreads();
    }

    float* red = (float*)abuf;
    if (kh == 1) {
#pragma unroll
        for (int mt = 0; mt < 6; mt++)
#pragma unroll
            for (int r = 0; r < 4; r++)
                red[(nsub * 96 + mt * 16 + quad * 4 + r) * 17 + col] = acc[mt][r];
    }
    __syncthreads();
    if (kh == 0) {
        int d = 2 * qd + pid, h = 2 * qh + pih;
        int vbase = (d * 32 + h) * 32 + piw;
#pragma unroll
        for (int mt = 0; mt < 6; mt++)
#pragma unroll
            for (int r = 0; r < 4; r++) {
                int m = mt * 16 + quad * 4 + r;
                if (m < 81) {
                    float v = acc[mt][r] + red[(nsub * 96 + m) * 17 + col] + b_off[m];
                    Pw[m * NVOX + vbase + 2 * col] = (_Float16)v;
                }
            }
    }
}

// ---------------------------------------------------------------------------
// Kernel B: LDS-staged deformable sample + GEMM + BN stats.
// Round-6 change: the gather is 16 inline-asm ds_read_b128 (rule-18 pattern)
// with staged s_waitcnt lgkmcnt(8)/(0) + sched_barrier(0). Asm outputs cannot
// be re-serialized by regalloc -> 16 reads in flight per wave, LDS pipe
// saturates by ILP alone. launch_bounds min dropped so the allocator can take
// ~130-160 VGPRs without spilling (2 blocks/CU is enough at this ILP).
// ---------------------------------------------------------------------------
#define DSR(dst, off) asm volatile("ds_read_b128 %0, %1" : "=v"(dst) : "v"(off))

#define CONS(xl, xh, Wx) do { \
    s00 += (Wx) * u2h2((unsigned)(xl)[0]); s01 += (Wx) * u2h2((unsigned)(xl)[1]); \
    s02 += (Wx) * u2h2((unsigned)(xl)[2]); s03 += (Wx) * u2h2((unsigned)(xl)[3]); \
    s10 += (Wx) * u2h2((unsigned)(xh)[0]); s11 += (Wx) * u2h2((unsigned)(xh)[1]); \
    s12 += (Wx) * u2h2((unsigned)(xh)[2]); s13 += (Wx) * u2h2((unsigned)(xh)[3]); \
} while (0)

#define GSLOW(Ax, wf) do { \
    half2v Wq_ = u2h2(dup16(wf)); \
    int4 xl_ = *(const int4*)(xtb + (Ax) + subLo); \
    int4 xh_ = *(const int4*)(xtb + (Ax) + subLo + 64); \
    t00 += Wq_ * u2h2((unsigned)xl_.x); t01 += Wq_ * u2h2((unsigned)xl_.y); \
    t02 += Wq_ * u2h2((unsigned)xl_.z); t03 += Wq_ * u2h2((unsigned)xl_.w); \
    t10 += Wq_ * u2h2((unsigned)xh_.x); t11 += Wq_ * u2h2((unsigned)xh_.y); \
    t12 += Wq_ * u2h2((unsigned)xh_.z); t13 += Wq_ * u2h2((unsigned)xh_.w); \
} while (0)

__global__ __launch_bounds__(256) void deform_kernel(
        const float* __restrict__ bias, float* ws, float* __restrict__ out) {
    __shared__ __align__(16) char region[25600];        // 200 cells x 128B, swizzled
    __shared__ __align__(16) int2 scratch[4][16][6];    // padded stride 48B, 3 KB
    // epilogue overlays (region is dead after the main loop):
    float* pbuf = (float*)region;                        // [2][2][16][17] = 8704 B
    float* rsumS = (float*)(region + 8704);              // [32]
    float* rsqS  = (float*)(region + 8704 + 128);        // [32]

    int tid = threadIdx.x, wave = tid >> 6, lane = tid & 63;
    int col = lane & 15, quad = lane >> 4;
    int bid = blockIdx.x;
    int d0 = (bid >> 6) << 1, h0 = ((bid >> 2) & 15) << 1, w0 = (bid & 3) << 3;

    const char* xtb = (const char*)(ws + WS_XT);
    const half8* wa8 = (const half8*)(ws + WS_WA);
    const _Float16* P = (const _Float16*)(ws + WS_P);
    float* gstat = ws + WS_STAT;

    int pdlo = (d0 >> 1) - 1, phlo = (h0 >> 1) - 1, pwlo = (w0 >> 1) - 1;

    // ---- stage region: 1600 16B chunks, coalesced, XOR-swizzled dest ----
#pragma unroll 1
    for (int it = 0; it < 7; it++) {
        int i = it * 256 + tid;
        if (i < 1600) {
            int r = i >> 3, c16 = i & 7;
            int rd = r / 40, rem = r - rd * 40, rh = rem >> 3, rw = rem & 7;
            int pd = min(max(pdlo + rd, 0), 17);
            int ph = min(max(phlo + rh, 0), 17);
            int pw = min(max(pwlo + rw, 0), 17);
            int cell = (pd * 18 + ph) * 18 + pw;
            int4 vsrc = *(const int4*)(xtb + cell * 128 + c16 * 16);
            int f = (r ^ (r >> 3)) & 7;
            *(int4*)(region + r * 128 + ((c16 ^ f) << 4)) = vsrc;
        }
    }
    __syncthreads();

    // ---- per-wave role ----
    int vh = wave & 1, kt = wave >> 1;
    int v = vh * 16 + col;
    int dv = v >> 4, hv = (v >> 3) & 1, wv = v & 7;
    int dcoord = d0 + dv, hcoord = h0 + hv, wcoord = w0 + wv;
    int gvox = dcoord * 1024 + hcoord * 32 + wcoord;
    int tbeg = kt ? 14 : 0, tend = kt ? 27 : 14;
    int subLo = quad * 16;
    unsigned uLo = (unsigned)subLo, uHi = uLo + 64u;
    unsigned rbase = (unsigned)(uintptr_t)(void*)region;   // LDS byte offset
    int bd = quad >> 1, bh = quad & 1;

    floatx4 acc0 = {0.f, 0.f, 0.f, 0.f}, acc1 = {0.f, 0.f, 0.f, 0.f};

    float od = (float)P[(3 * tbeg + 0) * NVOX + gvox];
    float oh = (float)P[(3 * tbeg + 1) * NVOX + gvox];
    float ow = (float)P[(3 * tbeg + 2) * NVOX + gvox];

#pragma unroll 1
    for (int tap = tbeg; tap < tend; tap++) {
        int kd = tap / 9, r9 = tap - kd * 9, kh2 = r9 / 3, kw2 = r9 - kh2 * 3;
        float pdc = (float)(dcoord + kd - 1) + od;
        float phc = (float)(hcoord + kh2 - 1) + oh;
        float pwc = (float)(wcoord + kw2 - 1) + ow;
        float fd0 = floorf(pdc), fh0 = floorf(phc), fw0 = floorf(pwc);
        float fd = pdc - fd0, fh = phc - fh0, fw = pwc - fw0;
        int id = (int)fd0, ih = (int)fh0, iw = (int)fw0;

        int cd0 = ((min(max(id,     -2), 33)) >> 1) + 1;
        int cd1 = ((min(max(id + 1, -2), 33)) >> 1) + 1;
        int ch0 = ((min(max(ih,     -2), 33)) >> 1) + 1;
        int ch1 = ((min(max(ih + 1, -2), 33)) >> 1) + 1;
        int cw0 = ((min(max(iw,     -2), 33)) >> 1) + 1;
        int cw1 = ((min(max(iw + 1, -2), 33)) >> 1) + 1;
        int sd0 = cd0 - pdlo, sd1 = cd1 - pdlo;
        int sh0 = ch0 - phlo, sh1 = ch1 - phlo;
        int sw0 = cw0 - pwlo, sw1 = cw1 - pwlo;
        bool oob = ((unsigned)sd0 > 4u) | ((unsigned)sd1 > 4u)
                 | ((unsigned)sh0 > 4u) | ((unsigned)sh1 > 4u)
                 | ((unsigned)sw0 > 7u) | ((unsigned)sw1 > 7u);

        // this lane builds corners (bd,bh,0) and (bd,bh,1)
        int sdq = bd ? sd1 : sd0, shq = bh ? sh1 : sh0;
        int rb = (sdq * 5 + shq) * 8;
        int r0 = rb + sw0, r1 = rb + sw1;
        int f0 = (r0 ^ (r0 >> 3)) & 7, f1 = (r1 ^ (r1 >> 3)) & 7;
        int a0 = oob ? 0x8000 : ((r0 << 7) | (f0 << 4));
        int a1 = oob ? 0x8000 : ((r1 << 7) | (f1 << 4));
        float gdw = 1.f - fd, ghw = 1.f - fh, gww = 1.f - fw;
        float wd = bd ? fd : gdw, wh = bh ? fh : ghw;
        float wdh = wd * wh;
        unsigned wb0 = (unsigned)__builtin_bit_cast(unsigned short, (_Float16)(wdh * gww));
        unsigned wb1 = (unsigned)__builtin_bit_cast(unsigned short, (_Float16)(wdh * fw));
        scratch[wave][col][quad] = make_int2(a0 | (a1 << 16), (int)(wb0 | (wb1 << 16)));

        if (tap + 1 < tend) {
            od = (float)P[(3 * tap + 3) * NVOX + gvox];
            oh = (float)P[(3 * tap + 4) * NVOX + gvox];
            ow = (float)P[(3 * tap + 5) * NVOX + gvox];
        }

        // A-fragments (global, vmcnt — in flight across the whole gather)
        int kb = tap * 8 + quad;
        half8 a00 = wa8[kb * 32 + col];
        half8 a01 = wa8[kb * 32 + 16 + col];
        half8 a10 = wa8[(kb + 4) * 32 + col];
        half8 a11 = wa8[(kb + 4) * 32 + 16 + col];

        // read back this voxel's full 8-corner table (broadcast across quads)
        const i4* sc = (const i4*)&scratch[wave][col][0];
        i4 pq0 = sc[0], pq1 = sc[1];

        unsigned A0 = (unsigned)pq0[0] & 0x7fffu;
        unsigned A1 = ((unsigned)pq0[0] >> 16) & 0x7fffu;
        unsigned A2 = (unsigned)pq0[2] & 0x7fffu;
        unsigned A3 = ((unsigned)pq0[2] >> 16) & 0x7fffu;
        unsigned A4 = (unsigned)pq1[0] & 0x7fffu;
        unsigned A5 = ((unsigned)pq1[0] >> 16) & 0x7fffu;
        unsigned A6 = (unsigned)pq1[2] & 0x7fffu;
        unsigned A7 = ((unsigned)pq1[2] >> 16) & 0x7fffu;

        // ---- 16 forced-ILP asm gathers (all in flight) ----
        i4 g0l, g0h, g1l, g1h, g2l, g2h, g3l, g3h;
        i4 g4l, g4h, g5l, g5h, g6l, g6h, g7l, g7h;
        DSR(g0l, rbase + (A0 ^ uLo)); DSR(g0h, rbase + (A0 ^ uHi));
        DSR(g1l, rbase + (A1 ^ uLo)); DSR(g1h, rbase + (A1 ^ uHi));
        DSR(g2l, rbase + (A2 ^ uLo)); DSR(g2h, rbase + (A2 ^ uHi));
        DSR(g3l, rbase + (A3 ^ uLo)); DSR(g3h, rbase + (A3 ^ uHi));
        DSR(g4l, rbase + (A4 ^ uLo)); DSR(g4h, rbase + (A4 ^ uHi));
        DSR(g5l, rbase + (A5 ^ uLo)); DSR(g5h, rbase + (A5 ^ uHi));
        DSR(g6l, rbase + (A6 ^ uLo)); DSR(g6h, rbase + (A6 ^ uHi));
        DSR(g7l, rbase + (A7 ^ uLo)); DSR(g7h, rbase + (A7 ^ uHi));

        half2v s00 = {0, 0}, s01 = {0, 0}, s02 = {0, 0}, s03 = {0, 0};
        half2v s10 = {0, 0}, s11 = {0, 0}, s12 = {0, 0}, s13 = {0, 0};

        asm volatile("s_waitcnt lgkmcnt(8)");
        __builtin_amdgcn_sched_barrier(0);
        {
            unsigned w01 = (unsigned)pq0[1], w23 = (unsigned)pq0[3];
            half2v W0 = u2h2((w01 & 0xffffu) * 0x10001u);
            half2v W1 = u2h2((w01 >> 16) * 0x10001u);
            half2v W2 = u2h2((w23 & 0xffffu) * 0x10001u);
            half2v W3 = u2h2((w23 >> 16) * 0x10001u);
            CONS(g0l, g0h, W0); CONS(g1l, g1h, W1);
            CONS(g2l, g2h, W2); CONS(g3l, g3h, W3);
        }
        asm volatile("s_waitcnt lgkmcnt(0)");
        __builtin_amdgcn_sched_barrier(0);
        {
            unsigned w45 = (unsigned)pq1[1], w67 = (unsigned)pq1[3];
            half2v W4 = u2h2((w45 & 0xffffu) * 0x10001u);
            half2v W5 = u2h2((w45 >> 16) * 0x10001u);
            half2v W6 = u2h2((w67 & 0xffffu) * 0x10001u);
            half2v W7 = u2h2((w67 >> 16) * 0x10001u);
            CONS(g4l, g4h, W4); CONS(g5l, g5h, W5);
            CONS(g6l, g6h, W6); CONS(g7l, g7h, W7);
        }

        // rare exact fallback for |off| >= 2 (global gather, verified path)
        if (__any((pq0[0] & 0x8000) != 0)) {
            bool flg = (pq0[0] & 0x8000) != 0;
            int Rd0 = ((min(max(id,     -2), 33) >> 1) + 1) * (324 * 128);
            int Rd1 = ((min(max(id + 1, -2), 33) >> 1) + 1) * (324 * 128);
            int Rh0 = ((min(max(ih,     -2), 33) >> 1) + 1) * (18 * 128);
            int Rh1 = ((min(max(ih + 1, -2), 33) >> 1) + 1) * (18 * 128);
            int Rw0 = ((min(max(iw,     -2), 33) >> 1) + 1) * 128;
            int Rw1 = ((min(max(iw + 1, -2), 33) >> 1) + 1) * 128;
            half2v t00 = {0,0}, t01 = {0,0}, t02 = {0,0}, t03 = {0,0};
            half2v t10 = {0,0}, t11 = {0,0}, t12 = {0,0}, t13 = {0,0};
            GSLOW(Rd0 + Rh0 + Rw0, gdw * ghw * gww);
            GSLOW(Rd0 + Rh0 + Rw1, gdw * ghw * fw);
            GSLOW(Rd0 + Rh1 + Rw0, gdw * fh  * gww);
            GSLOW(Rd0 + Rh1 + Rw1, gdw * fh  * fw);
            GSLOW(Rd1 + Rh0 + Rw0, fd  * ghw * gww);
            GSLOW(Rd1 + Rh0 + Rw1, fd  * ghw * fw);
            GSLOW(Rd1 + Rh1 + Rw0, fd  * fh  * gww);
            GSLOW(Rd1 + Rh1 + Rw1, fd  * fh  * fw);
            s00 = flg ? t00 : s00; s01 = flg ? t01 : s01;
            s02 = flg ? t02 : s02; s03 = flg ? t03 : s03;
            s10 = flg ? t10 : s10; s11 = flg ? t11 : s11;
            s12 = flg ? t12 : s12; s13 = flg ? t13 : s13;
        }

        half8 bf0 = pk8(s00, s01, s02, s03);
        half8 bf1 = pk8(s10, s11, s12, s13);

        acc0 = __builtin_amdgcn_mfma_f32_16x16x32_f16(a00, bf0, acc0, 0, 0, 0);
        acc1 = __builtin_amdgcn_mfma_f32_16x16x32_f16(a01, bf0, acc1, 0, 0, 0);
        acc0 = __builtin_amdgcn_mfma_f32_16x16x32_f16(a10, bf1, acc0, 0, 0, 0);
        acc1 = __builtin_amdgcn_mfma_f32_16x16x32_f16(a11, bf1, acc1, 0, 0, 0);
    }

    // ---- epilogue: region dead -> overlay pbuf/rsum ----
    __syncthreads();
    if (kt == 1) {
#pragma unroll
        for (int r = 0; r < 4; r++) {
            pbuf[((vh * 2 + 0) * 16 + quad * 4 + r) * 17 + col] = acc0[r];
            pbuf[((vh * 2 + 1) * 16 + quad * 4 + r) * 17 + col] = acc1[r];
        }
    }
    if (tid < 64) ((float*)(region + 8704))[tid] = 0.f;   // zero rsum+rsq (wave 0)
    __syncthreads();
    if (kt == 0) {
#pragma unroll
        for (int r = 0; r < 4; r++) {
            int i = quad * 4 + r;
            int o0 = i;
            float v0 = acc0[r] + pbuf[((vh * 2 + 0) * 16 + i) * 17 + col] + bias[o0];
            out[o0 * NVOX + gvox] = v0;
            atomicAdd(&rsumS[o0], v0);
            atomicAdd(&rsqS[o0], v0 * v0);
            int o1 = 16 + i;
            float v1 = acc1[r] + pbuf[((vh * 2 + 1) * 16 + i) * 17 + col] + bias[o1];
            out[o1 * NVOX + gvox] = v1;
            atomicAdd(&rsumS[o1], v1);
            atomicAdd(&rsqS[o1], v1 * v1);
        }
    }
    __syncthreads();
    if (tid < COUT) {
        atomicAdd(&gstat[tid], rsumS[tid]);
        atomicAdd(&gstat[COUT + tid], rsqS[tid]);
    }
}

// ---------------------------------------------------------------------------
// BN finalize + ReLU, in-place on d_out (unchanged).
// ---------------------------------------------------------------------------
__global__ void bn_kernel(const float* __restrict__ ws,
                          const float* __restrict__ gamma,
                          const float* __restrict__ beta,
                          float* out) {
    int i = blockIdx.x * 256 + threadIdx.x;
    int o = i >> 15;
    const float* gstat = ws + WS_STAT;
    const float inv = 1.f / 32768.f;
    float mean = gstat[o] * inv;
    float var  = gstat[COUT + o] * inv - mean * mean;
    float sc   = rsqrtf(var + 1e-5f) * gamma[o];
    float v = (out[i] - mean) * sc + beta[o];
    out[i] = fmaxf(v, 0.f);
}

// ---------------------------------------------------------------------------
extern "C" void kernel_launch(void* const* d_in, const int* in_sizes, int n_in,
                              void* d_out, int out_size, void* d_ws, size_t ws_size,
                              hipStream_t stream) {
    const float* x     = (const float*)d_in[0];
    const float* w_off = (const float*)d_in[1];
    const float* b_off = (const float*)d_in[2];
    const float* wmat  = (const float*)d_in[3];
    const float* bias  = (const float*)d_in[4];
    const float* gamma = (const float*)d_in[5];
    const float* beta  = (const float*)d_in[6];
    float* ws  = (float*)d_ws;
    float* out = (float*)d_out;

    prep_all_kernel<<<312, 256, 0, stream>>>(x, w_off, wmat, ws);
    offset_kernel<<<1024, 256, 0, stream>>>(b_off, ws);
    deform_kernel<<<1024, 256, 0, stream>>>(bias, ws, out);
    bn_kernel<<<4096, 256, 0, stream>>>(ws, gamma, beta, out);
}

// Round 8
// 145.150 us; speedup vs baseline: 1.0058x; 1.0058x over previous
//
#include <hip/hip_runtime.h>
#include <math.h>

// Problem constants
#define NVOX  32768     // 32^3 up-res voxels
#define CIN   64
#define COUT  32
#define KT    27
#define CIT   1728      // CIN*KT
#define PSP   5832      // 18^3 padded half-res spatial

// Workspace layout (float offsets)
#define WS_XT   0                 // fp16[5832][64] channel-last padded x
#define WS_WA   186624            // fp16[216][32][8] deform-W A-frags (K tap-major)
#define WS_WO   214272            // fp16[216][96][8] offset-W A-frags (M padded 81->96)
#define WS_STAT 297216            // [32] sum, [32] sumsq

typedef __attribute__((ext_vector_type(8))) _Float16 half8;
typedef __attribute__((ext_vector_type(2))) _Float16 half2v;
typedef __attribute__((ext_vector_type(4))) float floatx4;

static __device__ __forceinline__ unsigned dup16(float w) {
    unsigned short b = __builtin_bit_cast(unsigned short, (_Float16)w);
    return (unsigned)b * 0x10001u;
}
static __device__ __forceinline__ half2v u2h2(unsigned u) {
    return __builtin_bit_cast(half2v, u);
}
static __device__ __forceinline__ half8 pk8(half2v a, half2v b, half2v c, half2v d) {
    union { half8 v; half2v p[4]; } u;
    u.p[0] = a; u.p[1] = b; u.p[2] = c; u.p[3] = d;
    return u.v;
}

// ---------------------------------------------------------------------------
// Merged prep (round-4 version — verified):
//   blocks [0,92):    XT fill via LDS transpose
//   blocks [92,119):  pack wmat  -> WA
//   blocks [119,200): pack w_off -> WO (tap-major K)
//   block  200:       zero stats
// ---------------------------------------------------------------------------
__global__ __launch_bounds__(256) void prep_all_kernel(
        const float* __restrict__ x, const float* __restrict__ w_off,
        const float* __restrict__ wmat, float* __restrict__ ws) {
    int b = blockIdx.x, t = threadIdx.x;
    if (b < 92) {
        __shared__ _Float16 tile[64][65];
        _Float16* xth = (_Float16*)(ws + WS_XT);
        int tq = t >> 6, lane = t & 63;
        int base = b * 64;
        int cell = base + lane;
        int qw = cell % 18, qh = (cell / 18) % 18, qd = cell / 324;
        bool interior = (cell < PSP) && qd >= 1 && qd <= 16 && qh >= 1 && qh <= 16
                        && qw >= 1 && qw <= 16;
        int xbase = interior ? (((qd - 1) * 16 + (qh - 1)) * 16 + (qw - 1)) : 0;
#pragma unroll
        for (int i = 0; i < 16; i++) {
            int c = tq * 16 + i;
            float v = interior ? x[c * 4096 + xbase] : 0.f;
            tile[lane][c] = (_Float16)v;
        }
        __syncthreads();
#pragma unroll
        for (int i = 0; i < 16; i++) {
            int s = tq * 16 + i;
            int cell2 = base + s;
            if (cell2 < PSP) xth[cell2 * 64 + lane] = tile[s][lane];
        }
    } else if (b < 119) {
        _Float16* wa = (_Float16*)(ws + WS_WA);
        int idx = (b - 92) * 256 + t;           // 0..6911  (kb, o)
        int kb = idx >> 5, o = idx & 31;
        half8 r;
#pragma unroll
        for (int j = 0; j < 8; j++) {
            int kk = kb * 8 + j;                // K index, tap-major
            int tap = kk >> 6, ci = kk & 63;
            r[j] = (_Float16)wmat[o * CIT + ci * 27 + tap];
        }
        *(half8*)(wa + idx * 8) = r;
    } else if (b < 200) {
        _Float16* wo = (_Float16*)(ws + WS_WO);
        int idx = (b - 119) * 256 + t;          // 0..20735 = kb*96 + m
        int kb = idx / 96, m = idx % 96;
        half8 r;
#pragma unroll
        for (int j = 0; j < 8; j++) {
            int kk = kb * 8 + j;
            int tap = kk >> 6, ci = kk & 63;
            float v = (m < 81) ? w_off[(m * 64 + ci) * 27 + tap] : 0.f;
            r[j] = (_Float16)v;
        }
        *(half8*)(wo + idx * 8) = r;
    } else {
        if (t < 64) ws[WS_STAT + t] = 0.f;
    }
}

// ---------------------------------------------------------------------------
// Fused kernel: F0 offset GEMM (per-block N=32 slice, zero redundancy) -> LDS
// P_lds, then F1 = round-5 verified deform body reading offsets from LDS.
// LDS layout: F0: abuf dbuf [0..24576) + P_lds [28672..34816).
//             F1: region [0..25600) + scratch2 [25600..28672) + P_lds.
//             epilogue: pbuf/rsum overlay region (dead).
// ---------------------------------------------------------------------------
#define ACCP(xl, xh, Wx) do { \
    s00 += (Wx) * u2h2((unsigned)(xl).x); s01 += (Wx) * u2h2((unsigned)(xl).y); \
    s02 += (Wx) * u2h2((unsigned)(xl).z); s03 += (Wx) * u2h2((unsigned)(xl).w); \
    s10 += (Wx) * u2h2((unsigned)(xh).x); s11 += (Wx) * u2h2((unsigned)(xh).y); \
    s12 += (Wx) * u2h2((unsigned)(xh).z); s13 += (Wx) * u2h2((unsigned)(xh).w); \
} while (0)

#define DO2(ap, wp) do { \
    int a0_ = (ap) & 0x7fff, a1_ = (int)((((unsigned)(ap)) >> 16) & 0x7fffu); \
    unsigned wl_ = ((unsigned)(wp) & 0xffffu) * 0x10001u; \
    unsigned wh_ = (((unsigned)(wp)) >> 16) * 0x10001u; \
    int4 x0l_ = *(const int4*)(region + (a0_ ^ subLo)); \
    int4 x0h_ = *(const int4*)(region + (a0_ ^ subHi)); \
    int4 x1l_ = *(const int4*)(region + (a1_ ^ subLo)); \
    int4 x1h_ = *(const int4*)(region + (a1_ ^ subHi)); \
    ACCP(x0l_, x0h_, u2h2(wl_)); ACCP(x1l_, x1h_, u2h2(wh_)); \
} while (0)

#define GSLOW(Ax, wf) do { \
    half2v Wq_ = u2h2(dup16(wf)); \
    int4 xl_ = *(const int4*)(xtb + (Ax) + subLo); \
    int4 xh_ = *(const int4*)(xtb + (Ax) + subLo + 64); \
    t00 += Wq_ * u2h2((unsigned)xl_.x); t01 += Wq_ * u2h2((unsigned)xl_.y); \
    t02 += Wq_ * u2h2((unsigned)xl_.z); t03 += Wq_ * u2h2((unsigned)xl_.w); \
    t10 += Wq_ * u2h2((unsigned)xh_.x); t11 += Wq_ * u2h2((unsigned)xh_.y); \
    t12 += Wq_ * u2h2((unsigned)xh_.z); t13 += Wq_ * u2h2((unsigned)xh_.w); \
} while (0)

__global__ __launch_bounds__(256, 4) void fused_kernel(
        const float* __restrict__ b_off, const float* __restrict__ bias,
        float* ws, float* __restrict__ out) {
    __shared__ __align__(16) char shmem[34816];
    char* region = shmem;                                // 25600 B (F1)
    int2* scratch2 = (int2*)(shmem + 25600);             // [4][16][6] int2 (F1)
    _Float16* Pl = (_Float16*)(shmem + 28672);           // [96][32] fp16, 6144 B
    float* pbuf = (float*)shmem;                         // epilogue overlay
    float* rsumS = (float*)(shmem + 8704);               // [32]
    float* rsqS  = (float*)(shmem + 8832);               // [32]

    int tid = threadIdx.x, wave = tid >> 6, lane = tid & 63;
    int col = lane & 15, quad = lane >> 4;
    int bid = blockIdx.x;
    int d0 = (bid >> 6) << 1, h0 = ((bid >> 2) & 15) << 1, w0 = (bid & 3) << 3;

    const char* xtb = (const char*)(ws + WS_XT);
    const half8* wa8 = (const half8*)(ws + WS_WA);
    float* gstat = ws + WS_STAT;

    // ===================== F0: offset GEMM -> P_lds =====================
    {
        int4* ab4 = (int4*)shmem;
        const _Float16* abuf16 = (const _Float16*)shmem;
        const int4* wsrc = (const int4*)(ws + WS_WO);
        int nsub = wave & 1, mh = wave >> 1;             // mh in {0,1}
        int vv = nsub * 16 + col;
        int dA = d0 + (vv >> 4), hA = h0 + ((vv >> 3) & 1), wA = w0 + (vv & 7);

        // prologue: stage tap 0, preload tap 1 into regs
        int4 ra0 = wsrc[tid], ra1 = wsrc[256 + tid], ra2 = wsrc[512 + tid];
        ab4[tid] = ra0; ab4[256 + tid] = ra1; ab4[512 + tid] = ra2;
        ra0 = wsrc[768 + tid]; ra1 = wsrc[768 + 256 + tid]; ra2 = wsrc[768 + 512 + tid];

        // prefetch B for tap 0 (both K-halves)
        int c0;
        {
            int rd = ((dA - 1) >> 1) + 1, rh = ((hA - 1) >> 1) + 1, rw = ((wA - 1) >> 1) + 1;
            c0 = (rd * 18 + rh) * 18 + rw;
        }
        int4 bx0 = *(const int4*)(xtb + c0 * 128 + quad * 16);
        int4 bx1 = *(const int4*)(xtb + c0 * 128 + 64 + quad * 16);
        __syncthreads();

        floatx4 oacc[3];
#pragma unroll
        for (int mt = 0; mt < 3; mt++) oacc[mt] = (floatx4){0.f, 0.f, 0.f, 0.f};

#pragma unroll 1
        for (int tap = 0; tap < 27; tap++) {
            if (tap < 26) {                      // write tap+1 into other buffer
                int4* dst = ab4 + ((tap + 1) & 1) * 768;
                dst[tid] = ra0; dst[256 + tid] = ra1; dst[512 + tid] = ra2;
            }
            if (tap < 25) {                      // preload tap+2
                const int4* s2 = wsrc + (tap + 2) * 768;
                ra0 = s2[tid]; ra1 = s2[256 + tid]; ra2 = s2[512 + tid];
            }
            int4 nbx0 = bx0, nbx1 = bx1;
            if (tap < 26) {                      // prefetch next tap's B
                int tn = tap + 1;
                int kd = tn / 9, r9 = tn - kd * 9, kh2 = r9 / 3, kw2 = r9 - kh2 * 3;
                int rd = ((dA + kd - 1) >> 1) + 1;
                int rh = ((hA + kh2 - 1) >> 1) + 1;
                int rw = ((wA + kw2 - 1) >> 1) + 1;
                int nc = (rd * 18 + rh) * 18 + rw;
                nbx0 = *(const int4*)(xtb + nc * 128 + quad * 16);
                nbx1 = *(const int4*)(xtb + nc * 128 + 64 + quad * 16);
            }
            const _Float16* abh = abuf16 + (tap & 1) * 6144;
            half8 bf0 = __builtin_bit_cast(half8, bx0);
            half8 bf1 = __builtin_bit_cast(half8, bx1);
#pragma unroll
            for (int mt = 0; mt < 3; mt++) {
                half8 a0 = *(const half8*)(abh + quad * 768 + (mh * 48 + mt * 16 + col) * 8);
                oacc[mt] = __builtin_amdgcn_mfma_f32_16x16x32_f16(a0, bf0, oacc[mt], 0, 0, 0);
            }
#pragma unroll
            for (int mt = 0; mt < 3; mt++) {
                half8 a1 = *(const half8*)(abh + (4 + quad) * 768 + (mh * 48 + mt * 16 + col) * 8);
                oacc[mt] = __builtin_amdgcn_mfma_f32_16x16x32_f16(a1, bf1, oacc[mt], 0, 0, 0);
            }
            bx0 = nbx0; bx1 = nbx1;
            __syncthreads();
        }

        // write P slice (each wave owns 48 M-rows x its 16 voxels)
#pragma unroll
        for (int mt = 0; mt < 3; mt++)
#pragma unroll
            for (int r = 0; r < 4; r++) {
                int m = mh * 48 + mt * 16 + quad * 4 + r;
                if (m < 81)
                    Pl[m * 32 + vv] = (_Float16)(oacc[mt][r] + b_off[m]);
            }
        __syncthreads();   // P_lds ready; abuf dead -> region staging may begin
    }

    // ===================== F1: deform (round-5 body, P from LDS) ==========
    int pdlo = (d0 >> 1) - 1, phlo = (h0 >> 1) - 1, pwlo = (w0 >> 1) - 1;

#pragma unroll 1
    for (int it = 0; it < 7; it++) {
        int i = it * 256 + tid;
        if (i < 1600) {
            int r = i >> 3, c16 = i & 7;
            int rd = r / 40, rem = r - rd * 40, rh = rem >> 3, rw = rem & 7;
            int pd = min(max(pdlo + rd, 0), 17);
            int ph = min(max(phlo + rh, 0), 17);
            int pw = min(max(pwlo + rw, 0), 17);
            int cell = (pd * 18 + ph) * 18 + pw;
            int4 vsrc = *(const int4*)(xtb + cell * 128 + c16 * 16);
            int f = (r ^ (r >> 3)) & 7;
            *(int4*)(region + r * 128 + ((c16 ^ f) << 4)) = vsrc;
        }
    }
    __syncthreads();

    int vh = wave & 1, kt = wave >> 1;
    int v = vh * 16 + col;
    int dv = v >> 4, hv = (v >> 3) & 1, wv = v & 7;
    int dcoord = d0 + dv, hcoord = h0 + hv, wcoord = w0 + wv;
    int gvox = dcoord * 1024 + hcoord * 32 + wcoord;
    int tbeg = kt ? 14 : 0, tend = kt ? 27 : 14;
    int subLo = quad * 16, subHi = subLo + 64;
    int bd = quad >> 1, bh = quad & 1;

    floatx4 acc0 = {0.f, 0.f, 0.f, 0.f}, acc1 = {0.f, 0.f, 0.f, 0.f};

    float od = (float)Pl[(3 * tbeg + 0) * 32 + v];
    float oh = (float)Pl[(3 * tbeg + 1) * 32 + v];
    float ow = (float)Pl[(3 * tbeg + 2) * 32 + v];

#pragma unroll 1
    for (int tap = tbeg; tap < tend; tap++) {
        int kd = tap / 9, r9 = tap - kd * 9, kh2 = r9 / 3, kw2 = r9 - kh2 * 3;
        float pdc = (float)(dcoord + kd - 1) + od;
        float phc = (float)(hcoord + kh2 - 1) + oh;
        float pwc = (float)(wcoord + kw2 - 1) + ow;
        float fd0 = floorf(pdc), fh0 = floorf(phc), fw0 = floorf(pwc);
        float fd = pdc - fd0, fh = phc - fh0, fw = pwc - fw0;
        int id = (int)fd0, ih = (int)fh0, iw = (int)fw0;

        int cd0 = ((min(max(id,     -2), 33)) >> 1) + 1;
        int cd1 = ((min(max(id + 1, -2), 33)) >> 1) + 1;
        int ch0 = ((min(max(ih,     -2), 33)) >> 1) + 1;
        int ch1 = ((min(max(ih + 1, -2), 33)) >> 1) + 1;
        int cw0 = ((min(max(iw,     -2), 33)) >> 1) + 1;
        int cw1 = ((min(max(iw + 1, -2), 33)) >> 1) + 1;
        int sd0 = cd0 - pdlo, sd1 = cd1 - pdlo;
        int sh0 = ch0 - phlo, sh1 = ch1 - phlo;
        int sw0 = cw0 - pwlo, sw1 = cw1 - pwlo;
        bool oob = ((unsigned)sd0 > 4u) | ((unsigned)sd1 > 4u)
                 | ((unsigned)sh0 > 4u) | ((unsigned)sh1 > 4u)
                 | ((unsigned)sw0 > 7u) | ((unsigned)sw1 > 7u);

        int sdq = bd ? sd1 : sd0, shq = bh ? sh1 : sh0;
        int rb = (sdq * 5 + shq) * 8;
        int r0 = rb + sw0, r1 = rb + sw1;
        int f0 = (r0 ^ (r0 >> 3)) & 7, f1 = (r1 ^ (r1 >> 3)) & 7;
        int a0 = oob ? 0x8000 : ((r0 << 7) | (f0 << 4));
        int a1 = oob ? 0x8000 : ((r1 << 7) | (f1 << 4));
        float gdw = 1.f - fd, ghw = 1.f - fh, gww = 1.f - fw;
        float wd = bd ? fd : gdw, wh = bh ? fh : ghw;
        float wdh = wd * wh;
        unsigned wb0 = (unsigned)__builtin_bit_cast(unsigned short, (_Float16)(wdh * gww));
        unsigned wb1 = (unsigned)__builtin_bit_cast(unsigned short, (_Float16)(wdh * fw));
        scratch2[(wave * 16 + col) * 6 + quad] =
            make_int2(a0 | (a1 << 16), (int)(wb0 | (wb1 << 16)));

        if (tap + 1 < tend) {
            od = (float)Pl[(3 * tap + 3) * 32 + v];
            oh = (float)Pl[(3 * tap + 4) * 32 + v];
            ow = (float)Pl[(3 * tap + 5) * 32 + v];
        }

        int kb = tap * 8 + quad;
        half8 a00 = wa8[kb * 32 + col];
        half8 a01 = wa8[kb * 32 + 16 + col];
        half8 a10 = wa8[(kb + 4) * 32 + col];
        half8 a11 = wa8[(kb + 4) * 32 + 16 + col];

        const int4* sc = (const int4*)(scratch2 + (wave * 16 + col) * 6);
        int4 p0 = sc[0], p1 = sc[1];

        half2v s00 = {0, 0}, s01 = {0, 0}, s02 = {0, 0}, s03 = {0, 0};
        half2v s10 = {0, 0}, s11 = {0, 0}, s12 = {0, 0}, s13 = {0, 0};
        DO2(p0.x, p0.y); DO2(p0.z, p0.w);
        DO2(p1.x, p1.y); DO2(p1.z, p1.w);

        if (__any((p0.x & 0x8000) != 0)) {
            bool flg = (p0.x & 0x8000) != 0;
            int Rd0 = ((min(max(id,     -2), 33) >> 1) + 1) * (324 * 128);
            int Rd1 = ((min(max(id + 1, -2), 33) >> 1) + 1) * (324 * 128);
            int Rh0 = ((min(max(ih,     -2), 33) >> 1) + 1) * (18 * 128);
            int Rh1 = ((min(max(ih + 1, -2), 33) >> 1) + 1) * (18 * 128);
            int Rw0 = ((min(max(iw,     -2), 33) >> 1) + 1) * 128;
            int Rw1 = ((min(max(iw + 1, -2), 33) >> 1) + 1) * 128;
            half2v t00 = {0,0}, t01 = {0,0}, t02 = {0,0}, t03 = {0,0};
            half2v t10 = {0,0}, t11 = {0,0}, t12 = {0,0}, t13 = {0,0};
            GSLOW(Rd0 + Rh0 + Rw0, gdw * ghw * gww);
            GSLOW(Rd0 + Rh0 + Rw1, gdw * ghw * fw);
            GSLOW(Rd0 + Rh1 + Rw0, gdw * fh  * gww);
            GSLOW(Rd0 + Rh1 + Rw1, gdw * fh  * fw);
            GSLOW(Rd1 + Rh0 + Rw0, fd  * ghw * gww);
            GSLOW(Rd1 + Rh0 + Rw1, fd  * ghw * fw);
            GSLOW(Rd1 + Rh1 + Rw0, fd  * fh  * gww);
            GSLOW(Rd1 + Rh1 + Rw1, fd  * fh  * fw);
            s00 = flg ? t00 : s00; s01 = flg ? t01 : s01;
            s02 = flg ? t02 : s02; s03 = flg ? t03 : s03;
            s10 = flg ? t10 : s10; s11 = flg ? t11 : s11;
            s12 = flg ? t12 : s12; s13 = flg ? t13 : s13;
        }

        half8 bf0 = pk8(s00, s01, s02, s03);
        half8 bf1 = pk8(s10, s11, s12, s13);

        acc0 = __builtin_amdgcn_mfma_f32_16x16x32_f16(a00, bf0, acc0, 0, 0, 0);
        acc1 = __builtin_amdgcn_mfma_f32_16x16x32_f16(a01, bf0, acc1, 0, 0, 0);
        acc0 = __builtin_amdgcn_mfma_f32_16x16x32_f16(a10, bf1, acc0, 0, 0, 0);
        acc1 = __builtin_amdgcn_mfma_f32_16x16x32_f16(a11, bf1, acc1, 0, 0, 0);
    }

    // ---- epilogue: region dead -> overlay pbuf/rsum ----
    __syncthreads();
    if (kt == 1) {
#pragma unroll
        for (int r = 0; r < 4; r++) {
            pbuf[((vh * 2 + 0) * 16 + quad * 4 + r) * 17 + col] = acc0[r];
            pbuf[((vh * 2 + 1) * 16 + quad * 4 + r) * 17 + col] = acc1[r];
        }
    }
    if (tid < 64) ((float*)(shmem + 8704))[tid] = 0.f;   // zero rsumS+rsqS
    __syncthreads();
    if (kt == 0) {
#pragma unroll
        for (int r = 0; r < 4; r++) {
            int i = quad * 4 + r;
            int o0 = i;
            float v0 = acc0[r] + pbuf[((vh * 2 + 0) * 16 + i) * 17 + col] + bias[o0];
            out[o0 * NVOX + gvox] = v0;
            atomicAdd(&rsumS[o0], v0);
            atomicAdd(&rsqS[o0], v0 * v0);
            int o1 = 16 + i;
            float v1 = acc1[r] + pbuf[((vh * 2 + 1) * 16 + i) * 17 + col] + bias[o1];
            out[o1 * NVOX + gvox] = v1;
            atomicAdd(&rsumS[o1], v1);
            atomicAdd(&rsqS[o1], v1 * v1);
        }
    }
    __syncthreads();
    if (tid < COUT) {
        atomicAdd(&gstat[tid], rsumS[tid]);
        atomicAdd(&gstat[COUT + tid], rsqS[tid]);
    }
}

// ---------------------------------------------------------------------------
// BN finalize + ReLU, in-place on d_out (unchanged).
// ---------------------------------------------------------------------------
__global__ void bn_kernel(const float* __restrict__ ws,
                          const float* __restrict__ gamma,
                          const float* __restrict__ beta,
                          float* out) {
    int i = blockIdx.x * 256 + threadIdx.x;
    int o = i >> 15;
    const float* gstat = ws + WS_STAT;
    const float inv = 1.f / 32768.f;
    float mean = gstat[o] * inv;
    float var  = gstat[COUT + o] * inv - mean * mean;
    float sc   = rsqrtf(var + 1e-5f) * gamma[o];
    float v = (out[i] - mean) * sc + beta[o];
    out[i] = fmaxf(v, 0.f);
}

// ---------------------------------------------------------------------------
extern "C" void kernel_launch(void* const* d_in, const int* in_sizes, int n_in,
                              void* d_out, int out_size, void* d_ws, size_t ws_size,
                              hipStream_t stream) {
    const float* x     = (const float*)d_in[0];
    const float* w_off = (const float*)d_in[1];
    const float* b_off = (const float*)d_in[2];
    const float* wmat  = (const float*)d_in[3];
    const float* bias  = (const float*)d_in[4];
    const float* gamma = (const float*)d_in[5];
    const float* beta  = (const float*)d_in[6];
    float* ws  = (float*)d_ws;
    float* out = (float*)d_out;

    prep_all_kernel<<<201, 256, 0, stream>>>(x, w_off, wmat, ws);
    fused_kernel<<<1024, 256, 0, stream>>>(b_off, bias, ws, out);
    bn_kernel<<<4096, 256, 0, stream>>>(ws, gamma, beta, out);
}